// Round 1
// baseline (662.617 us; speedup 1.0000x reference)
//
#include <hip/hip_runtime.h>
#include <hip/hip_bf16.h>

#define N_NODES 50000
#define N_EDGES 800000
#define N_GRAPHS 64
#define HID 64

static inline size_t align256(size_t x) { return (x + 255) & ~(size_t)255; }

__global__ void zero_i32(int* __restrict__ p, int n) {
    int i = blockIdx.x * blockDim.x + threadIdx.x;
    if (i < n) p[i] = 0;
}

// count incoming edges per destination node
__global__ void deg_kernel(const int* __restrict__ ei, int* __restrict__ cnt) {
    int e = blockIdx.x * blockDim.x + threadIdx.x;
    if (e < N_EDGES) atomicAdd(&cnt[ei[N_EDGES + e]], 1);
}

// single-block exclusive scan -> row_ptr[0..N], row_ptr[i+1] = sum cnt[0..i]
__global__ void scan_kernel(const int* __restrict__ cnt, int* __restrict__ row_ptr) {
    __shared__ int sdata[1024];
    __shared__ int base;
    int tid = threadIdx.x;
    if (tid == 0) base = 0;
    __syncthreads();
    for (int start = 0; start < N_NODES; start += 1024) {
        int i = start + tid;
        int v = (i < N_NODES) ? cnt[i] : 0;
        sdata[tid] = v;
        __syncthreads();
        for (int off = 1; off < 1024; off <<= 1) {
            int t = (tid >= off) ? sdata[tid - off] : 0;
            __syncthreads();
            sdata[tid] += t;
            __syncthreads();
        }
        if (i < N_NODES) row_ptr[i + 1] = base + sdata[tid];
        __syncthreads();
        if (tid == 0) base += sdata[1023];
        __syncthreads();
    }
    if (tid == 0) row_ptr[0] = 0;
}

// dinv = 1/sqrt(deg+1); fill_ptr = row_ptr copy for atomic bucket fill
__global__ void dinv_kernel(const int* __restrict__ cnt, const int* __restrict__ row_ptr,
                            float* __restrict__ dinv, int* __restrict__ fill_ptr) {
    int i = blockIdx.x * blockDim.x + threadIdx.x;
    if (i < N_NODES) {
        dinv[i] = rsqrtf((float)cnt[i] + 1.0f);
        fill_ptr[i] = row_ptr[i];
    }
}

// scatter edge sources into CSR buckets keyed by dst
__global__ void fill_kernel(const int* __restrict__ ei, int* __restrict__ fill_ptr,
                            int* __restrict__ csr_src) {
    int e = blockIdx.x * blockDim.x + threadIdx.x;
    if (e < N_EDGES) {
        int src = ei[e];
        int dst = ei[N_EDGES + e];
        int pos = atomicAdd(&fill_ptr[dst], 1);
        csr_src[pos] = src;
    }
}

// batch is sorted: find first node index with batch >= g, for g = 0..N_GRAPHS
__global__ void gstart_kernel(const int* __restrict__ batch, int* __restrict__ gstart) {
    int g = threadIdx.x;
    if (g <= N_GRAPHS) {
        int lo = 0, hi = N_NODES;
        while (lo < hi) {
            int mid = (lo + hi) >> 1;
            if (batch[mid] < g) lo = mid + 1; else hi = mid;
        }
        gstart[g] = lo;
    }
}

// hw[row][col] = sum_k h[row*K+k] * W[k*64+col]; one wave per row (64 cols)
__global__ __launch_bounds__(256) void matmul_kernel(const float* __restrict__ h,
                                                     const float* __restrict__ W,
                                                     float* __restrict__ hw, int K) {
    int idx = blockIdx.x * blockDim.x + threadIdx.x;
    int row = idx >> 6;
    int col = idx & 63;
    if (row >= N_NODES) return;
    const float* hr = h + (size_t)row * K;
    float acc = 0.f;
#pragma unroll 8
    for (int k = 0; k < K; ++k) acc += hr[k] * W[k * 64 + col];
    hw[row * 64 + col] = acc;
}

// per node (one wave): agg = dinv[i]*(sum_e dinv[src]*hw[src] + dinv[i]*hw[i]) + b
// then L2-normalize across 64 dims and ReLU.
__global__ __launch_bounds__(256) void agg_kernel(const float* __restrict__ hw,
                                                  const int* __restrict__ row_ptr,
                                                  const int* __restrict__ csr_src,
                                                  const float* __restrict__ dinv,
                                                  const float* __restrict__ b,
                                                  float* __restrict__ hout) {
    int node = blockIdx.x * (blockDim.x >> 6) + (threadIdx.x >> 6);
    int lane = threadIdx.x & 63;
    if (node >= N_NODES) return;
    int s = row_ptr[node], e = row_ptr[node + 1];
    float di = dinv[node];
    float acc = di * hw[(size_t)node * 64 + lane];
    for (int idx = s; idx < e; ++idx) {
        int src = csr_src[idx];
        acc += dinv[src] * hw[(size_t)src * 64 + lane];
    }
    float val = di * acc + b[lane];
    float sq = val * val;
#pragma unroll
    for (int off = 32; off >= 1; off >>= 1) sq += __shfl_xor(sq, off, 64);
    float nrm = sqrtf(sq);
    float r = val / fmaxf(nrm, 1e-12f);
    hout[(size_t)node * 64 + lane] = fmaxf(r, 0.f);
}

// one block per graph: mean+max pool over contiguous node range, then 128x32 linear
__global__ __launch_bounds__(256) void pool_linear_kernel(const float* __restrict__ h,
                                                          const int* __restrict__ gstart,
                                                          const float* __restrict__ Wl,
                                                          const float* __restrict__ bl,
                                                          float* __restrict__ out) {
    int g = blockIdx.x;
    int s = gstart[g], e = gstart[g + 1];
    int lane = threadIdx.x & 63;
    int wid = threadIdx.x >> 6;  // 0..3
    float sum = 0.f, mx = -3.4e38f;
    for (int i = s + wid; i < e; i += 4) {
        float v = h[(size_t)i * 64 + lane];
        sum += v;
        mx = fmaxf(mx, v);
    }
    __shared__ float ssum[4][64];
    __shared__ float smx[4][64];
    __shared__ float pooled[128];
    ssum[wid][lane] = sum;
    smx[wid][lane] = mx;
    __syncthreads();
    if (wid == 0) {
        float s4 = ssum[0][lane] + ssum[1][lane] + ssum[2][lane] + ssum[3][lane];
        float m4 = fmaxf(fmaxf(smx[0][lane], smx[1][lane]), fmaxf(smx[2][lane], smx[3][lane]));
        int cntg = e - s;
        float mean = s4 / fmaxf((float)cntg, 1.0f);
        if (cntg == 0) m4 = 0.f;
        pooled[lane] = mean;
        pooled[64 + lane] = m4;
    }
    __syncthreads();
    if (threadIdx.x < 32) {
        int j = threadIdx.x;
        float acc = bl[j];
#pragma unroll 8
        for (int k = 0; k < 128; ++k) acc += pooled[k] * Wl[k * 32 + j];
        out[g * 32 + j] = acc;
    }
}

extern "C" void kernel_launch(void* const* d_in, const int* in_sizes, int n_in,
                              void* d_out, int out_size, void* d_ws, size_t ws_size,
                              hipStream_t stream) {
    const float* x        = (const float*)d_in[0];   // 50000 x 128
    const int*   ei       = (const int*)d_in[1];     // 2 x 800000
    const int*   batch    = (const int*)d_in[2];     // 50000
    const float* W1       = (const float*)d_in[3];   // 128 x 64
    const float* b1       = (const float*)d_in[4];
    const float* W2       = (const float*)d_in[5];   // 64 x 64
    const float* b2       = (const float*)d_in[6];
    const float* W3       = (const float*)d_in[7];   // 64 x 64
    const float* b3       = (const float*)d_in[8];
    const float* Wl       = (const float*)d_in[9];   // 128 x 32
    const float* bl       = (const float*)d_in[10];
    float* out = (float*)d_out;

    char* ws = (char*)d_ws;
    int*   cnt      = (int*)ws;                 ws += align256((size_t)N_NODES * 4);
    int*   row_ptr  = (int*)ws;                 ws += align256((size_t)(N_NODES + 1) * 4);
    int*   fill_ptr = (int*)ws;                 ws += align256((size_t)N_NODES * 4);
    float* dinv     = (float*)ws;               ws += align256((size_t)N_NODES * 4);
    int*   gstart   = (int*)ws;                 ws += align256((size_t)(N_GRAPHS + 1) * 4);
    int*   csr_src  = (int*)ws;                 ws += align256((size_t)N_EDGES * 4);
    float* hwb      = (float*)ws;               ws += align256((size_t)N_NODES * 64 * 4);
    float* h1       = (float*)ws;               ws += align256((size_t)N_NODES * 64 * 4);
    float* h2       = (float*)ws;               ws += align256((size_t)N_NODES * 64 * 4);

    hipLaunchKernelGGL(zero_i32, dim3((N_NODES + 255) / 256), dim3(256), 0, stream, cnt, N_NODES);
    hipLaunchKernelGGL(deg_kernel, dim3((N_EDGES + 255) / 256), dim3(256), 0, stream, ei, cnt);
    hipLaunchKernelGGL(scan_kernel, dim3(1), dim3(1024), 0, stream, cnt, row_ptr);
    hipLaunchKernelGGL(dinv_kernel, dim3((N_NODES + 255) / 256), dim3(256), 0, stream,
                       cnt, row_ptr, dinv, fill_ptr);
    hipLaunchKernelGGL(fill_kernel, dim3((N_EDGES + 255) / 256), dim3(256), 0, stream,
                       ei, fill_ptr, csr_src);
    hipLaunchKernelGGL(gstart_kernel, dim3(1), dim3(128), 0, stream, batch, gstart);

    const int mm_grid = (N_NODES * 64 + 255) / 256;
    const int agg_grid = (N_NODES + 3) / 4;  // 4 waves per block, wave per node

    // layer 1: x(128) @ W1 -> hw; agg -> h1
    hipLaunchKernelGGL(matmul_kernel, dim3(mm_grid), dim3(256), 0, stream, x, W1, hwb, 128);
    hipLaunchKernelGGL(agg_kernel, dim3(agg_grid), dim3(256), 0, stream,
                       hwb, row_ptr, csr_src, dinv, b1, h1);
    // layer 2: h1(64) @ W2 -> hw; agg -> h2
    hipLaunchKernelGGL(matmul_kernel, dim3(mm_grid), dim3(256), 0, stream, h1, W2, hwb, 64);
    hipLaunchKernelGGL(agg_kernel, dim3(agg_grid), dim3(256), 0, stream,
                       hwb, row_ptr, csr_src, dinv, b2, h2);
    // layer 3: h2(64) @ W3 -> hw; agg -> h1
    hipLaunchKernelGGL(matmul_kernel, dim3(mm_grid), dim3(256), 0, stream, h2, W3, hwb, 64);
    hipLaunchKernelGGL(agg_kernel, dim3(agg_grid), dim3(256), 0, stream,
                       hwb, row_ptr, csr_src, dinv, b3, h1);

    // pooling + final linear
    hipLaunchKernelGGL(pool_linear_kernel, dim3(N_GRAPHS), dim3(256), 0, stream,
                       h1, gstart, Wl, bl, out);
}